// Round 2
// baseline (77.799 us; speedup 1.0000x reference)
//
#include <hip/hip_runtime.h>
#include <math.h>

// FullyConnectedVQCs — single fused kernel (R9).
//
// R8 (two kernels: build_M 17x1KB to global, then vqc) measured 64.5us with
// neither kernel in the rocprof top-5 => large inter-dispatch overhead.
// R9 fuses: each block rebuilds all 17 circuit matrices M_real (32x16, f16
// A-fragment order) into LDS (17408 B), then runs the 5-stage network for
// 64 batch rows (2 row-groups x 4 circuit-slot waves = 8 waves, 512 thr).
// 512 blocks = exactly 2 blocks/CU, 16 waves/CU (same occupancy as R8).
//
// Per stage per wave: 4 sincos + ~30 VALU B-pack -> 1 v_mfma_f32_32x32x16_f16
// -> |amp|^2 + signed sums -> ONE shfl_xor(32) per expval. Double-buffered
// component-major LDS H[2][16][64]; 1 barrier/stage.

typedef _Float16 half8 __attribute__((ext_vector_type(8)));
typedef float floatx16 __attribute__((ext_vector_type(16)));

#define N_CIRC 17
// Composed CNOT-ring permutation per SEL layer (range r=1,2,3):
// new_state[PERM[r-1][i]] = old_state[i]. Qubit q <-> bit (8>>q).
__device__ __constant__ constexpr int PERM[3][16] = {
  {0, 9, 11, 2, 15, 6, 4, 13, 7, 14, 12, 5, 8, 1, 3, 10},   // r=1
  {0, 5, 10, 15, 1, 4, 11, 14, 2, 7, 8, 13, 3, 6, 9, 12},   // r=2
  {0, 3, 6, 5, 12, 15, 10, 9, 11, 8, 13, 14, 7, 4, 1, 2},   // r=3
};

// Block = 64 batch rows (2 row-groups of 32) x 4 circuit-slot waves.
__global__ void __launch_bounds__(512, 4) vqc_fused_kernel(
    const float* __restrict__ x, const float* __restrict__ theta,
    float* __restrict__ out, int B) {
  // M_real for all 17 circuits in f16 A-fragment order:
  // half index (c*64 + ((k>>3)<<5 | m))*8 + (k&7), m = lane&31, k = input amp.
  __shared__ _Float16 Mlds[N_CIRC * 64 * 8] __attribute__((aligned(16)));
  __shared__ float Hb[2][16][64];   // [buf][component][row-in-block]

  const int tid  = threadIdx.x;
  const int w8   = tid >> 6;               // wave 0..7
  const int rg   = w8 >> 2;                // row-group 0/1
  const int w    = w8 & 3;                 // circuit slot 0..3
  const int lane = tid & 63;
  const int g = lane >> 5, n = lane & 31;  // k-group, row-in-group
  const int nn = rg * 32 + n;              // row in block 0..63
  const int row_base = blockIdx.x * 64;

  // ---- load x into buf 0: H = [0, x(13), 0, 0] (coalesced) ----
  for (int i = tid; i < 64 * 13; i += 512) {
    int r = i / 13, j = i - 13 * r;
    Hb[0][1 + j][r] = (row_base + r < B) ? x[(row_base + r) * 13 + j] : 0.f;
  }
  if (tid < 64) { Hb[0][0][tid] = 0.f; Hb[0][14][tid] = 0.f; Hb[0][15][tid] = 0.f; }

  // ---- build M for all 17 circuits: thread t<272 -> (circuit c, column j).
  // Runs the gate chain on REAL basis vector e_j; column j of M_real is
  // [Re a_0, Im a_0, Re a_1, Im a_1, ...] of the result.
  if (tid < N_CIRC * 16) {
    const int c = tid >> 4, j = tid & 15;
    int tt, blk;
    if (c < 4)       { tt = 0; blk = c; }
    else if (c < 8)  { tt = 3; blk = c - 4; }
    else if (c < 12) { tt = 4; blk = c - 8; }
    else if (c < 16) { tt = 1; blk = c - 12; }
    else             { tt = 2; blk = 0; }
    float sr[16], si[16];
#pragma unroll
    for (int i = 0; i < 16; ++i) { sr[i] = 0.f; si[i] = 0.f; }
    sr[j] = 1.f;
#pragma unroll
    for (int l = 0; l < 4; ++l) {
#pragma unroll
      for (int q = 0; q < 4; ++q) {
        // theta shape (5,4,4,4,3): [tt][blk][l][q][k]
        const float* th = theta + (((tt * 4 + blk) * 16) + l * 4 + q) * 3;
        float phi = th[0], the = th[1], ome = th[2];
        float st, ct;   __sincosf(0.5f * the, &st, &ct);
        float sap, cap; __sincosf(0.5f * (phi + ome), &sap, &cap);
        float sam, cam; __sincosf(0.5f * (phi - ome), &sam, &cam);
        float u00r =  cap * ct, u00i = -sap * ct;
        float u01r = -cam * st, u01i = -sam * st;
        float u10r =  cam * st, u10i = -sam * st;
        float u11r =  cap * ct, u11i =  sap * ct;
        const int m = 8 >> q;
#pragma unroll
        for (int i = 0; i < 16; ++i) {
          if (i & m) continue;
          const int i1 = i | m;
          float ar = sr[i], ai = si[i], br = sr[i1], bi = si[i1];
          sr[i]  = u00r * ar - u00i * ai + u01r * br - u01i * bi;
          si[i]  = u00r * ai + u00i * ar + u01r * bi + u01i * br;
          sr[i1] = u10r * ar - u10i * ai + u11r * br - u11i * bi;
          si[i1] = u10r * ai + u10i * ar + u11r * bi + u11i * br;
        }
      }
      const int ri = (l == 3) ? 0 : l;  // SEL ranges 1,2,3,1
      float tr[16], ti[16];
#pragma unroll
      for (int i = 0; i < 16; ++i) { tr[i] = sr[i]; ti[i] = si[i]; }
#pragma unroll
      for (int i = 0; i < 16; ++i) { sr[PERM[ri][i]] = tr[i]; si[PERM[ri][i]] = ti[i]; }
    }
#pragma unroll
    for (int m = 0; m < 32; ++m) {
      float val = (m & 1) ? si[m >> 1] : sr[m >> 1];
      int ln = ((j >> 3) << 5) | m;
      Mlds[(c * 64 + ln) * 8 + (j & 7)] = (_Float16)val;
    }
  }
  __syncthreads();

  float e_final = 0.f;

#pragma unroll
  for (int s = 0; s < 5; ++s) {
    const int rb = s & 1, wb = rb ^ 1;       // read / write buffer
    const bool active = (s < 4) || (w == 0);
    const int ci = (s < 4) ? (s * 4 + w) : 16;
    // ---- stage inputs (4 angles) for row nn ----
    float x0, x1, x2, x3;
    if (s == 0) {        // 'first': contiguous block w
      x0 = Hb[rb][4 * w + 0][nn]; x1 = Hb[rb][4 * w + 1][nn];
      x2 = Hb[rb][4 * w + 2][nn]; x3 = Hb[rb][4 * w + 3][nn];
    } else if (s < 4) {  // 'multiple': x_i = E[circuit i][component w]
      x0 = Hb[rb][w][nn];      x1 = Hb[rb][4 + w][nn];
      x2 = Hb[rb][8 + w][nn];  x3 = Hb[rb][12 + w][nn];
    } else {             // final: angles = stage-3 readouts
      x0 = Hb[rb][0][nn]; x1 = Hb[rb][1][nn];
      x2 = Hb[rb][2][nn]; x3 = Hb[rb][3][nn];
    }

    float le0 = 0.f, le1 = 0.f, le2 = 0.f, le3 = 0.f;
    if (active) {
      // A-fragment from LDS (16B aligned, one ds_read_b128)
      half8 a = *(const half8*)&Mlds[(ci * 64 + lane) * 8];
      // ---- B-fragment: real product state, lane supplies k = 8g..8g+7 ----
      // amp(k), k=b3b2b1b0: w0[b3] w1[b2] w2[b1] w3[b0]; b3 = g.
      float s0, c0, s1, c1, s2, c2, s3, c3;
      __sincosf(0.5f * x0, &s0, &c0);
      __sincosf(0.5f * x1, &s1, &c1);
      __sincosf(0.5f * x2, &s2, &c2);
      __sincosf(0.5f * x3, &s3, &c3);
      float w0 = g ? s0 : c0;
      float u0 = w0 * c1, u1 = w0 * s1;          // b2 = 0 / 1
      float w23[4] = {c2 * c3, c2 * s3, s2 * c3, s2 * s3};
      half8 bf;
#pragma unroll
      for (int t = 0; t < 8; ++t)
        bf[t] = (_Float16)(((t < 4) ? u0 : u1) * w23[t & 3]);
      // ---- one MFMA: D(32x32) = M_real(32x16) x States(16x32) ----
      floatx16 z = {0.f,0.f,0.f,0.f,0.f,0.f,0.f,0.f,
                    0.f,0.f,0.f,0.f,0.f,0.f,0.f,0.f};
      floatx16 acc = __builtin_amdgcn_mfma_f32_32x32x16_f16(a, bf, z, 0, 0, 0);
      // D layout (measured m74/m101): col = lane&31 = n,
      // row m = (reg&3) + 8*(reg>>2) + 4*g, reg 0..15.
      // m = 2*amp + (im?): amp = 4*qq + 2*g + (rr>>1), part = rr&1.
      float p[4][2];
#pragma unroll
      for (int qq = 0; qq < 4; ++qq)
#pragma unroll
        for (int h = 0; h < 2; ++h)
          p[qq][h] = acc[4 * qq + 2 * h]     * acc[4 * qq + 2 * h]
                   + acc[4 * qq + 2 * h + 1] * acc[4 * qq + 2 * h + 1];
      // amp bits: b0 = h, b1 = g, b2 = qq&1, b3 = qq>>1
      float S4[4], D4[4];
#pragma unroll
      for (int qq = 0; qq < 4; ++qq) {
        S4[qq] = p[qq][0] + p[qq][1];
        D4[qq] = p[qq][0] - p[qq][1];
      }
      le0 = (S4[0] + S4[1]) - (S4[2] + S4[3]);             // sign by b3
      le0 += __shfl_xor(le0, 32);
      if (s < 3) {
        le1 = (S4[0] - S4[1]) + (S4[2] - S4[3]);           // sign by b2
        float S = (S4[0] + S4[1]) + (S4[2] + S4[3]);
        le2 = g ? -S : S;                                  // sign by b1 = g
        le3 = (D4[0] + D4[1]) + (D4[2] + D4[3]);           // sign by b0
        le1 += __shfl_xor(le1, 32);
        le2 += __shfl_xor(le2, 32);
        le3 += __shfl_xor(le3, 32);
      }
    }
    // ---- write stage outputs to the other buffer ----
    if (s < 3) {
      if (g == 0) {      // 32 lanes/wave, distinct banks
        Hb[wb][4 * w + 0][nn] = le0; Hb[wb][4 * w + 1][nn] = le1;
        Hb[wb][4 * w + 2][nn] = le2; Hb[wb][4 * w + 3][nn] = le3;
      }
    } else if (s == 3) {
      if (g == 0) Hb[wb][w][nn] = le0;
    } else {
      e_final = le0;
    }
    __syncthreads();     // writes visible; also fences rb reads vs next writes
  }

  if (w == 0 && g == 0 && row_base + nn < B) {
    const float MULT = (float)(3.141592653589793 - 1.1920928955078125e-07);
    out[row_base + nn] = e_final * MULT;
  }
}

extern "C" void kernel_launch(void* const* d_in, const int* in_sizes, int n_in,
                              void* d_out, int out_size, void* d_ws, size_t ws_size,
                              hipStream_t stream) {
  const float* x     = (const float*)d_in[0];
  const float* theta = (const float*)d_in[1];
  float* out = (float*)d_out;
  int B = in_sizes[0] / 13;       // 32768
  int blocks = (B + 63) / 64;     // 512 blocks x 8 waves = exactly 2/CU
  hipLaunchKernelGGL(vqc_fused_kernel, dim3(blocks), dim3(512), 0, stream,
                     x, theta, out, B);
}

// Round 3
// 64.943 us; speedup vs baseline: 1.1979x; 1.1979x over previous
//
#include <hip/hip_runtime.h>
#include <math.h>

// FullyConnectedVQCs — R10: register-resident network, zero barriers.
//
// R8 (two kernels, LDS H-exchange, 1 barrier/stage): 64.5us. R9 (fused
// build): 77.8us — per-block redundant build regressed 13us; reverted.
// Profile shows dur ~= harness 256MiB poison-fill (~41us, fixed) + kernels,
// so vqc itself is ~19us — far above its ~4us latency physics. The excess
// is the barrier-lockstep LDS exchange. R10 removes it:
//
// One wave owns 32 batch rows through the ENTIRE 5-stage network. Per stage
// it computes all 4 circuits (4 MFMAs). After the shfl_xor(32) reduce each
// lane n holds all 16 expvals of row n, so the stage-to-stage 'multiple'
// transpose is compile-time register re-indexing: no LDS, no syncthreads.
// 1024 blocks x 64 threads = 4 independent waves/CU.

typedef _Float16 half8 __attribute__((ext_vector_type(8)));
typedef float floatx16 __attribute__((ext_vector_type(16)));

#define N_CIRC 17
// Composed CNOT-ring permutation per SEL layer (range r=1,2,3):
// new_state[PERM[r-1][i]] = old_state[i]. Qubit q <-> bit (8>>q).
__device__ __constant__ constexpr int PERM[3][16] = {
  {0, 9, 11, 2, 15, 6, 4, 13, 7, 14, 12, 5, 8, 1, 3, 10},   // r=1
  {0, 5, 10, 15, 1, 4, 11, 14, 2, 7, 8, 13, 3, 6, 9, 12},   // r=2
  {0, 3, 6, 5, 12, 15, 10, 9, 11, 8, 13, 14, 7, 4, 1, 2},   // r=3
};

// Build M_real (32x16: real 32-dim output reps x 16 REAL input amps) for all
// 17 circuits in f16 A-fragment order for mfma_f32_32x32x16_f16:
// A[m][k]: m = lane&31, k = (lane>>5)*8 + j  (8 halves per lane).
// half index: (c*64 + ((k>>3)<<5 | m))*8 + (k&7).
// Thread (c,j) runs the gate chain on REAL basis vector e_j; column j of
// M_real is [Re a_0, Im a_0, Re a_1, Im a_1, ...] of the result.
__global__ void __launch_bounds__(64) build_M_kernel(
    const float* __restrict__ theta, _Float16* __restrict__ M) {
  int idx = blockIdx.x * 64 + threadIdx.x;
  if (idx >= N_CIRC * 16) return;
  int c = idx >> 4, j = idx & 15;
  int tt, blk;
  if (c < 4)       { tt = 0; blk = c; }
  else if (c < 8)  { tt = 3; blk = c - 4; }
  else if (c < 12) { tt = 4; blk = c - 8; }
  else if (c < 16) { tt = 1; blk = c - 12; }
  else             { tt = 2; blk = 0; }
  float sr[16], si[16];
#pragma unroll
  for (int i = 0; i < 16; ++i) { sr[i] = 0.f; si[i] = 0.f; }
  sr[j] = 1.f;
#pragma unroll
  for (int l = 0; l < 4; ++l) {
#pragma unroll
    for (int q = 0; q < 4; ++q) {
      // theta shape (5,4,4,4,3): [tt][blk][l][q][k]
      const float* th = theta + (((tt * 4 + blk) * 16) + l * 4 + q) * 3;
      float phi = th[0], the = th[1], ome = th[2];
      float st, ct;   __sincosf(0.5f * the, &st, &ct);
      float sap, cap; __sincosf(0.5f * (phi + ome), &sap, &cap);
      float sam, cam; __sincosf(0.5f * (phi - ome), &sam, &cam);
      float u00r =  cap * ct, u00i = -sap * ct;
      float u01r = -cam * st, u01i = -sam * st;
      float u10r =  cam * st, u10i = -sam * st;
      float u11r =  cap * ct, u11i =  sap * ct;
      const int m = 8 >> q;
#pragma unroll
      for (int i = 0; i < 16; ++i) {
        if (i & m) continue;
        const int i1 = i | m;
        float ar = sr[i], ai = si[i], br = sr[i1], bi = si[i1];
        sr[i]  = u00r * ar - u00i * ai + u01r * br - u01i * bi;
        si[i]  = u00r * ai + u00i * ar + u01r * bi + u01i * br;
        sr[i1] = u10r * ar - u10i * ai + u11r * br - u11i * bi;
        si[i1] = u10r * ai + u10i * ar + u11r * bi + u11i * br;
      }
    }
    const int ri = (l == 3) ? 0 : l;  // SEL ranges 1,2,3,1
    float tr[16], ti[16];
#pragma unroll
    for (int i = 0; i < 16; ++i) { tr[i] = sr[i]; ti[i] = si[i]; }
#pragma unroll
    for (int i = 0; i < 16; ++i) { sr[PERM[ri][i]] = tr[i]; si[PERM[ri][i]] = ti[i]; }
  }
#pragma unroll
  for (int m = 0; m < 32; ++m) {
    float val = (m & 1) ? si[m >> 1] : sr[m >> 1];
    int lane = ((j >> 3) << 5) | m;
    M[(size_t)(c * 64 + lane) * 8 + (j & 7)] = (_Float16)val;
  }
}

// One circuit for 32 rows: angles a0..a3 (per-lane, row n), returns expvals
// (full: 4 of them, else just o0) summed across both k-halves via shfl.
__device__ __forceinline__ void run_circ(
    const _Float16* __restrict__ M, int ci, int lane, int g,
    float a0, float a1, float a2, float a3, bool full,
    float& o0, float& o1, float& o2, float& o3) {
  float s0, c0, s1, c1, s2, c2, s3, c3;
  __sincosf(0.5f * a0, &s0, &c0);
  __sincosf(0.5f * a1, &s1, &c1);
  __sincosf(0.5f * a2, &s2, &c2);
  __sincosf(0.5f * a3, &s3, &c3);
  // B-fragment: real product state; lane supplies k = 8g..8g+7.
  // amp(k), k=b3b2b1b0: w0[b3] w1[b2] w2[b1] w3[b0]; b3 = g.
  float w0 = g ? s0 : c0;
  float u0 = w0 * c1, u1 = w0 * s1;          // b2 = 0 / 1
  float w23[4] = {c2 * c3, c2 * s3, s2 * c3, s2 * s3};
  half8 bf;
#pragma unroll
  for (int t = 0; t < 8; ++t)
    bf[t] = (_Float16)(((t < 4) ? u0 : u1) * w23[t & 3]);
  half8 a = *(const half8*)&M[(size_t)(ci * 64 + lane) * 8];
  floatx16 z = {0.f,0.f,0.f,0.f,0.f,0.f,0.f,0.f,
                0.f,0.f,0.f,0.f,0.f,0.f,0.f,0.f};
  floatx16 acc = __builtin_amdgcn_mfma_f32_32x32x16_f16(a, bf, z, 0, 0, 0);
  // D layout (measured m74/m101): col = lane&31 = n,
  // row m = (reg&3) + 8*(reg>>2) + 4*g. m = 2*amp + (im?):
  // amp = 4*qq + 2*g + (rr>>1), part = rr&1, with qq=reg>>2, rr=reg&3.
  float p[4][2];
#pragma unroll
  for (int qq = 0; qq < 4; ++qq)
#pragma unroll
    for (int h = 0; h < 2; ++h)
      p[qq][h] = acc[4 * qq + 2 * h]     * acc[4 * qq + 2 * h]
               + acc[4 * qq + 2 * h + 1] * acc[4 * qq + 2 * h + 1];
  // amp bits: b0 = h, b1 = g, b2 = qq&1, b3 = qq>>1
  float S4[4], D4[4];
#pragma unroll
  for (int qq = 0; qq < 4; ++qq) {
    S4[qq] = p[qq][0] + p[qq][1];
    D4[qq] = p[qq][0] - p[qq][1];
  }
  o0 = (S4[0] + S4[1]) - (S4[2] + S4[3]);               // sign by b3
  o0 += __shfl_xor(o0, 32);
  if (full) {
    o1 = (S4[0] - S4[1]) + (S4[2] - S4[3]);             // sign by b2
    float S = (S4[0] + S4[1]) + (S4[2] + S4[3]);
    o2 = g ? -S : S;                                    // sign by b1 = g
    o3 = (D4[0] + D4[1]) + (D4[2] + D4[3]);             // sign by b0
    o1 += __shfl_xor(o1, 32);
    o2 += __shfl_xor(o2, 32);
    o3 += __shfl_xor(o3, 32);
  }
}

// One wave = 32 batch rows through the whole network. No LDS, no barriers.
__global__ void __launch_bounds__(64) vqc_reg_kernel(
    const float* __restrict__ x, const _Float16* __restrict__ M,
    float* __restrict__ out, int B) {
  const int lane = threadIdx.x;            // 0..63
  const int g = lane >> 5, n = lane & 31;  // k-group, row-in-wave
  const int row = blockIdx.x * 32 + n;

  // per-lane x row (both halves read the same row: L1 broadcast)
  float xv[13];
  const float* xp = x + (size_t)(row < B ? row : 0) * 13;
#pragma unroll
  for (int j = 0; j < 13; ++j) xv[j] = xp[j];

  float e[4][4];   // e[circuit][expval] of current stage
  float d0 = 0.f, d1 = 0.f, d2 = 0.f;

  // stage 0 ('first' wiring): circuit w reads H[4w..4w+3], H=[0,x(13),0,0]
  run_circ(M, 0, lane, g, 0.f,    xv[0],  xv[1],  xv[2],  true,
           e[0][0], e[0][1], e[0][2], e[0][3]);
  run_circ(M, 1, lane, g, xv[3],  xv[4],  xv[5],  xv[6],  true,
           e[1][0], e[1][1], e[1][2], e[1][3]);
  run_circ(M, 2, lane, g, xv[7],  xv[8],  xv[9],  xv[10], true,
           e[2][0], e[2][1], e[2][2], e[2][3]);
  run_circ(M, 3, lane, g, xv[11], xv[12], 0.f,    0.f,    true,
           e[3][0], e[3][1], e[3][2], e[3][3]);

  // stages 1-2 ('multiple' wiring): circuit w reads e[0..3][w] — a pure
  // register transpose (this replaces R8's LDS exchange + barrier).
#pragma unroll
  for (int s = 1; s <= 2; ++s) {
    float ne[4][4];
#pragma unroll
    for (int w = 0; w < 4; ++w)
      run_circ(M, s * 4 + w, lane, g, e[0][w], e[1][w], e[2][w], e[3][w],
               true, ne[w][0], ne[w][1], ne[w][2], ne[w][3]);
#pragma unroll
    for (int w = 0; w < 4; ++w)
#pragma unroll
      for (int j = 0; j < 4; ++j) e[w][j] = ne[w][j];
  }

  // stage 3 (16->4 readout): circuits 12..15, one expval each
  float f[4];
#pragma unroll
  for (int w = 0; w < 4; ++w)
    run_circ(M, 12 + w, lane, g, e[0][w], e[1][w], e[2][w], e[3][w],
             false, f[w], d0, d1, d2);

  // stage 4 (4->1): circuit 16
  float r;
  run_circ(M, 16, lane, g, f[0], f[1], f[2], f[3], false, r, d0, d1, d2);

  if (g == 0 && row < B) {
    const float MULT = (float)(3.141592653589793 - 1.1920928955078125e-07);
    out[row] = r * MULT;
  }
}

extern "C" void kernel_launch(void* const* d_in, const int* in_sizes, int n_in,
                              void* d_out, int out_size, void* d_ws, size_t ws_size,
                              hipStream_t stream) {
  const float* x     = (const float*)d_in[0];
  const float* theta = (const float*)d_in[1];
  float* out = (float*)d_out;
  _Float16* M = (_Float16*)d_ws;  // 17*64*8 halves = 17408 B
  int B = in_sizes[0] / 13;       // 32768
  hipLaunchKernelGGL(build_M_kernel, dim3((N_CIRC * 16 + 63) / 64), dim3(64),
                     0, stream, theta, M);
  int blocks = (B + 31) / 32;     // 1024 one-wave blocks = 4 waves/CU
  hipLaunchKernelGGL(vqc_reg_kernel, dim3(blocks), dim3(64), 0, stream,
                     x, M, out, B);
}

// Round 5
// 61.931 us; speedup vs baseline: 1.2562x; 1.0486x over previous
//
#include <hip/hip_runtime.h>
#include <math.h>

// FullyConnectedVQCs — R12: amp-parallel build_M (PERM_INV[1] FIXED) +
// register-resident vqc.
//
// Model from R8-R10: dur ~= 60-61us fixed harness floor (256MiB poison fill
// ~40us @83% HBM peak + reset memset train) + ~4us ours. vqc restructuring
// (LDS-lockstep R8 vs zero-barrier R10) moves dur <0.5us => vqc ~1-2us.
// Remaining addressable cost: build_M serial chain + dispatch gap.
//
// R11 failed (absmax 0.74): PERM_INV[1] was wrongly written as the 4x4
// transpose; correct inverse of PERM[1]={0,5,10,15,1,4,11,14,2,7,8,13,
// 3,6,9,12} is {0,4,8,12,5,1,13,9,10,14,2,6,15,11,7,3}. Rows 0,2 verified
// unchanged. R12 = R11 + that one-row fix.
//
// build_M: thread = (circuit, column j, amp i), 17 blocks x 256 thr. Each
// Rot butterfly = coefficient-select + __shfl_xor(m) partner swap
// (m in {8,4,2,1}, within 16-lane column group); CNOT-layer permutation =
// one __shfl via inverse-perm lane table.

typedef _Float16 half8 __attribute__((ext_vector_type(8)));
typedef float floatx16 __attribute__((ext_vector_type(16)));

#define N_CIRC 17
// Composed CNOT-ring permutation per SEL layer (range r=1,2,3):
// new_state[PERM[r-1][i]] = old_state[i]. Qubit q <-> bit (8>>q).
// PERM_INV[r][p] = i s.t. PERM[r][i] = p (source amp for new position p).
__device__ __constant__ constexpr int PERM_INV[3][16] = {
  {0, 13, 3, 14, 6, 11, 5, 8, 12, 1, 15, 2, 10, 7, 9, 4},   // r=1
  {0, 4, 8, 12, 5, 1, 13, 9, 10, 14, 2, 6, 15, 11, 7, 3},   // r=2 (FIXED)
  {0, 14, 15, 1, 13, 3, 2, 12, 9, 7, 6, 8, 4, 10, 11, 5},   // r=3
};

// Build M_real (32x16: real 32-dim output reps x 16 REAL input amps) for all
// 17 circuits in f16 A-fragment order for mfma_f32_32x32x16_f16:
// A[m][k]: m = lane&31, k = (lane>>5)*8 + j  (8 halves per lane).
// half index: (c*64 + ((k>>3)<<5 | m))*8 + (k&7).
// Block c, thread (j = tid>>4, i = tid&15): carries amp i of the chain run
// on REAL basis vector e_j. Butterfly partners via shfl_xor (same 16-lane
// column group); layer permutation via shfl with PERM_INV lane table.
__global__ void __launch_bounds__(256) build_M_kernel(
    const float* __restrict__ theta, _Float16* __restrict__ M) {
  const int c   = blockIdx.x;
  const int tid = threadIdx.x;
  const int j   = tid >> 4;          // column 0..15
  const int i   = tid & 15;          // amp 0..15
  const int lane = tid & 63;
  int tt, blk;
  if (c < 4)       { tt = 0; blk = c; }
  else if (c < 8)  { tt = 3; blk = c - 4; }
  else if (c < 12) { tt = 4; blk = c - 8; }
  else if (c < 16) { tt = 1; blk = c - 12; }
  else             { tt = 2; blk = 0; }

  float sr = (i == j) ? 1.f : 0.f;
  float si = 0.f;

#pragma unroll
  for (int l = 0; l < 4; ++l) {
#pragma unroll
    for (int q = 0; q < 4; ++q) {
      // theta shape (5,4,4,4,3): [tt][blk][l][q][k]
      const float* th = theta + (((tt * 4 + blk) * 16) + l * 4 + q) * 3;
      float phi = th[0], the = th[1], ome = th[2];
      float st, ct;   __sincosf(0.5f * the, &st, &ct);
      float sap, cap; __sincosf(0.5f * (phi + ome), &sap, &cap);
      float sam, cam; __sincosf(0.5f * (phi - ome), &sam, &cam);
      float u00r =  cap * ct, u00i = -sap * ct;
      float u01r = -cam * st, u01i = -sam * st;
      float u10r =  cam * st, u10i = -sam * st;
      float u11r =  cap * ct, u11i =  sap * ct;
      const int m = 8 >> q;
      // partner amp value
      float pr = __shfl_xor(sr, m);
      float pi = __shfl_xor(si, m);
      const bool hi = (i & m) != 0;
      // coeff on self / on partner (complex):
      // low  i: new = u00*self + u01*partner
      // high i: new = u11*self + u10*partner
      float car = hi ? u11r : u00r, cai = hi ? u11i : u00i;
      float cbr = hi ? u10r : u01r, cbi = hi ? u10i : u01i;
      float nsr = car * sr - cai * si + cbr * pr - cbi * pi;
      float nsi = car * si + cai * sr + cbr * pi + cbi * pr;
      sr = nsr; si = nsi;
    }
    const int ri = (l == 3) ? 0 : l;  // SEL ranges 1,2,3,1
    // new_state[i] = old_state[PERM_INV[ri][i]]
    const int src = (lane & ~15) | PERM_INV[ri][i];
    sr = __shfl(sr, src);
    si = __shfl(si, src);
  }
  // write real (m=2i) and imag (m=2i+1) rows of column j
  const int ln0 = ((j >> 3) << 5) | (2 * i);
  M[(size_t)(c * 64 + ln0) * 8 + (j & 7)]       = (_Float16)sr;
  M[(size_t)(c * 64 + (ln0 | 1)) * 8 + (j & 7)] = (_Float16)si;
}

// One circuit for 32 rows: angles a0..a3 (per-lane, row n), returns expvals
// (full: 4 of them, else just o0) summed across both k-halves via shfl.
__device__ __forceinline__ void run_circ(
    const _Float16* __restrict__ M, int ci, int lane, int g,
    float a0, float a1, float a2, float a3, bool full,
    float& o0, float& o1, float& o2, float& o3) {
  float s0, c0, s1, c1, s2, c2, s3, c3;
  __sincosf(0.5f * a0, &s0, &c0);
  __sincosf(0.5f * a1, &s1, &c1);
  __sincosf(0.5f * a2, &s2, &c2);
  __sincosf(0.5f * a3, &s3, &c3);
  // B-fragment: real product state; lane supplies k = 8g..8g+7.
  // amp(k), k=b3b2b1b0: w0[b3] w1[b2] w2[b1] w3[b0]; b3 = g.
  float w0 = g ? s0 : c0;
  float u0 = w0 * c1, u1 = w0 * s1;          // b2 = 0 / 1
  float w23[4] = {c2 * c3, c2 * s3, s2 * c3, s2 * s3};
  half8 bf;
#pragma unroll
  for (int t = 0; t < 8; ++t)
    bf[t] = (_Float16)(((t < 4) ? u0 : u1) * w23[t & 3]);
  half8 a = *(const half8*)&M[(size_t)(ci * 64 + lane) * 8];
  floatx16 z = {0.f,0.f,0.f,0.f,0.f,0.f,0.f,0.f,
                0.f,0.f,0.f,0.f,0.f,0.f,0.f,0.f};
  floatx16 acc = __builtin_amdgcn_mfma_f32_32x32x16_f16(a, bf, z, 0, 0, 0);
  // D layout (measured m74/m101): col = lane&31 = n,
  // row m = (reg&3) + 8*(reg>>2) + 4*g. m = 2*amp + (im?):
  // amp = 4*qq + 2*g + (rr>>1), part = rr&1, with qq=reg>>2, rr=reg&3.
  float p[4][2];
#pragma unroll
  for (int qq = 0; qq < 4; ++qq)
#pragma unroll
    for (int h = 0; h < 2; ++h)
      p[qq][h] = acc[4 * qq + 2 * h]     * acc[4 * qq + 2 * h]
               + acc[4 * qq + 2 * h + 1] * acc[4 * qq + 2 * h + 1];
  // amp bits: b0 = h, b1 = g, b2 = qq&1, b3 = qq>>1
  float S4[4], D4[4];
#pragma unroll
  for (int qq = 0; qq < 4; ++qq) {
    S4[qq] = p[qq][0] + p[qq][1];
    D4[qq] = p[qq][0] - p[qq][1];
  }
  o0 = (S4[0] + S4[1]) - (S4[2] + S4[3]);               // sign by b3
  o0 += __shfl_xor(o0, 32);
  if (full) {
    o1 = (S4[0] - S4[1]) + (S4[2] - S4[3]);             // sign by b2
    float S = (S4[0] + S4[1]) + (S4[2] + S4[3]);
    o2 = g ? -S : S;                                    // sign by b1 = g
    o3 = (D4[0] + D4[1]) + (D4[2] + D4[3]);             // sign by b0
    o1 += __shfl_xor(o1, 32);
    o2 += __shfl_xor(o2, 32);
    o3 += __shfl_xor(o3, 32);
  }
}

// One wave = 32 batch rows through the whole network. No LDS, no barriers.
__global__ void __launch_bounds__(64) vqc_reg_kernel(
    const float* __restrict__ x, const _Float16* __restrict__ M,
    float* __restrict__ out, int B) {
  const int lane = threadIdx.x;            // 0..63
  const int g = lane >> 5, n = lane & 31;  // k-group, row-in-wave
  const int row = blockIdx.x * 32 + n;

  // per-lane x row (both halves read the same row: L1 broadcast)
  float xv[13];
  const float* xp = x + (size_t)(row < B ? row : 0) * 13;
#pragma unroll
  for (int j = 0; j < 13; ++j) xv[j] = xp[j];

  float e[4][4];   // e[circuit][expval] of current stage
  float d0 = 0.f, d1 = 0.f, d2 = 0.f;

  // stage 0 ('first' wiring): circuit w reads H[4w..4w+3], H=[0,x(13),0,0]
  run_circ(M, 0, lane, g, 0.f,    xv[0],  xv[1],  xv[2],  true,
           e[0][0], e[0][1], e[0][2], e[0][3]);
  run_circ(M, 1, lane, g, xv[3],  xv[4],  xv[5],  xv[6],  true,
           e[1][0], e[1][1], e[1][2], e[1][3]);
  run_circ(M, 2, lane, g, xv[7],  xv[8],  xv[9],  xv[10], true,
           e[2][0], e[2][1], e[2][2], e[2][3]);
  run_circ(M, 3, lane, g, xv[11], xv[12], 0.f,    0.f,    true,
           e[3][0], e[3][1], e[3][2], e[3][3]);

  // stages 1-2 ('multiple' wiring): circuit w reads e[0..3][w] — a pure
  // register transpose (no LDS, no barriers).
#pragma unroll
  for (int s = 1; s <= 2; ++s) {
    float ne[4][4];
#pragma unroll
    for (int w = 0; w < 4; ++w)
      run_circ(M, s * 4 + w, lane, g, e[0][w], e[1][w], e[2][w], e[3][w],
               true, ne[w][0], ne[w][1], ne[w][2], ne[w][3]);
#pragma unroll
    for (int w = 0; w < 4; ++w)
#pragma unroll
      for (int j = 0; j < 4; ++j) e[w][j] = ne[w][j];
  }

  // stage 3 (16->4 readout): circuits 12..15, one expval each
  float f[4];
#pragma unroll
  for (int w = 0; w < 4; ++w)
    run_circ(M, 12 + w, lane, g, e[0][w], e[1][w], e[2][w], e[3][w],
             false, f[w], d0, d1, d2);

  // stage 4 (4->1): circuit 16
  float r;
  run_circ(M, 16, lane, g, f[0], f[1], f[2], f[3], false, r, d0, d1, d2);

  if (g == 0 && row < B) {
    const float MULT = (float)(3.141592653589793 - 1.1920928955078125e-07);
    out[row] = r * MULT;
  }
}

extern "C" void kernel_launch(void* const* d_in, const int* in_sizes, int n_in,
                              void* d_out, int out_size, void* d_ws, size_t ws_size,
                              hipStream_t stream) {
  const float* x     = (const float*)d_in[0];
  const float* theta = (const float*)d_in[1];
  float* out = (float*)d_out;
  _Float16* M = (_Float16*)d_ws;  // 17*64*8 halves = 17408 B
  int B = in_sizes[0] / 13;       // 32768
  hipLaunchKernelGGL(build_M_kernel, dim3(N_CIRC), dim3(256), 0, stream,
                     theta, M);
  int blocks = (B + 31) / 32;     // 1024 one-wave blocks = 4 waves/CU
  hipLaunchKernelGGL(vqc_reg_kernel, dim3(blocks), dim3(64), 0, stream,
                     x, M, out, B);
}